// Round 8
// baseline (128.677 us; speedup 1.0000x reference)
//
#include <hip/hip_runtime.h>
#include <cstddef>

#define TT 1024
#define DDIM 512
#define HH 8
#define NND 64           // interpolation nodes per (b,h): h^4 cubic error ~6e-5, safe
#define NS 68            // node row stride (floats): 64 d + Z at [64]

typedef __attribute__((ext_vector_type(8))) short bfrag;   // 8 bf16 (4 VGPRs)
typedef __attribute__((ext_vector_type(4))) float facc;    // 4 fp32 acc

#define SC2   2.8853900817779268f   // 2*log2(e)
#define L2E   1.4426950408889634f

static __device__ __forceinline__ unsigned bfrne(float f) {
    unsigned u = __float_as_uint(f);
    return (u + 0x7fffu + ((u >> 16) & 1u)) >> 16;
}
static __device__ __forceinline__ unsigned pack2rne(float a, float b) {
    return bfrne(a) | (bfrne(b) << 16);
}
static __device__ __forceinline__ unsigned pack2hu(float a, float b) {
    return ((__float_as_uint(a) + 0x8000u) >> 16) |
           ((__float_as_uint(b) + 0x8000u) & 0xffff0000u);
}
static __device__ __forceinline__ void gl2lds16(const void* g, void* l) {
    __builtin_amdgcn_global_load_lds(
        (const __attribute__((address_space(1))) unsigned int*)g,
        (__attribute__((address_space(3))) unsigned int*)l, 16, 0, 0);
}
// w from pre-multiplied t = exp2(z2_node)*exp2(kv2):  w = exp(tanh(z)) = e^{1-2/(t+1)}
static __device__ __forceinline__ float wt(float t) {
    float r = __builtin_amdgcn_rcpf(t + 1.f);
    return __builtin_amdgcn_exp2f(fmaf(r, -2.f * L2E, L2E));
}

// ---- K1: fused prepare ---------------------------------------------------------
__global__ __launch_bounds__(256) void prepare_kernel(
    const float* __restrict__ x, const float* __restrict__ Wk,
    const float* __restrict__ Wp, const float* __restrict__ Wq,
    const float* __restrict__ bq, const float* __restrict__ wm,
    unsigned short* __restrict__ xb, unsigned short* __restrict__ WkT,
    unsigned short* __restrict__ WpT, unsigned short* __restrict__ vq2b,
    float* __restrict__ qsb2)
{
    const int bx = blockIdx.x, tid = threadIdx.x;
    const int lane = tid & 63, wave = tid >> 6;
    if (bx < 2048) {
        const int row = bx * 4 + wave;
        const float4* xr = (const float4*)(x + (size_t)row * DDIM);
        float4 x0 = xr[lane * 2], x1 = xr[lane * 2 + 1];
        uint4 st;
        st.x = pack2rne(x0.x, x0.y); st.y = pack2rne(x0.z, x0.w);
        st.z = pack2rne(x1.x, x1.y); st.w = pack2rne(x1.z, x1.w);
        int p = lane ^ (row & 7);
        *(uint4*)(xb + (size_t)row * DDIM + p * 8) = st;
    } else if (bx < 2176) {
        int idx = bx - 2048;
        const float* src = (idx & 64) ? Wp : Wk;
        unsigned short* dst = (idx & 64) ? WpT : WkT;
        idx &= 63;
        const int n0 = (idx & 7) * 64, k0 = (idx >> 3) * 64;
        __shared__ float sT[64][65];
        #pragma unroll
        for (int it = 0; it < 4; ++it) {
            int task = it * 256 + tid;
            int kr = task >> 4, c4 = (task & 15) * 4;
            float4 v = *(const float4*)(src + (size_t)(k0 + kr) * DDIM + n0 + c4);
            sT[kr][c4] = v.x; sT[kr][c4 + 1] = v.y; sT[kr][c4 + 2] = v.z; sT[kr][c4 + 3] = v.w;
        }
        __syncthreads();
        #pragma unroll
        for (int it = 0; it < 2; ++it) {
            int task = it * 256 + tid;
            int n = task >> 3, kg = task & 7;
            unsigned u[4];
            #pragma unroll
            for (int jj = 0; jj < 4; ++jj)
                u[jj] = pack2rne(sT[kg * 8 + jj * 2][n], sT[kg * 8 + jj * 2 + 1][n]);
            int p = ((k0 >> 3) + kg) ^ (n & 7);
            uint4 st; st.x = u[0]; st.y = u[1]; st.z = u[2]; st.w = u[3];
            *(uint4*)(dst + (size_t)(n0 + n) * DDIM + p * 8) = st;
        }
    } else {
        int idx = (bx - 2176) * 4 + wave;   // 0..4095
        int h = idx >> 9, d = idx & 511;
        float v = Wq[(size_t)d * DDIM + h * 64 + lane] * wm[64 + lane];
        #pragma unroll
        for (int off = 32; off > 0; off >>= 1) v += __shfl_xor(v, off);
        if (lane == 0) vq2b[h * DDIM + d] = (unsigned short)bfrne(v * SC2);
        if (bx == 2176 && tid < HH) {
            float sb = 0.f;
            for (int j = 0; j < 64; ++j)
                sb = fmaf(bq[tid * 64 + j], wm[64 + j], sb);
            qsb2[tid] = sb * SC2;
        }
    }
}

// ---- K2: GEMM1 kx = xb @ WkT + bk. Tile 64 t x 128 n, grid 512 = 2 blocks/CU. --
__global__ __launch_bounds__(256) void gemm1_kernel(
    const unsigned short* __restrict__ A, const unsigned short* __restrict__ B,
    const float* __restrict__ bias, unsigned short* __restrict__ kxTg,
    float* __restrict__ ks2, const float* __restrict__ wm,
    const unsigned short* __restrict__ vq2b, const float* __restrict__ qsb2,
    float* __restrict__ qs2)
{
    // 2 bufs x (A 4096 | B 8192) = 24576 shorts + svq 1024; epi eT 2x4608 reuses buf0
    __shared__ __align__(16) unsigned short smem[25600];
    unsigned short* svq = smem + 24576;
    const int tid = threadIdx.x, lane = tid & 63, wave = tid >> 6;
    const int l15 = lane & 15, quad = lane >> 4;
    const int wr = wave >> 1, wc = wave & 1;           // 2x2 wave grid: 32 rows x 64 cols
    const int row0 = blockIdx.x * 64, colpair = blockIdx.y;
    const int h = colpair * 2 + wc, n0 = colpair * 128;

    const float qsbh = qsb2[h];
    float bvv[4], wmv[4];
    #pragma unroll
    for (int nt = 0; nt < 4; ++nt) {
        bvv[nt] = bias[h * 64 + nt * 16 + l15];
        wmv[nt] = wm[nt * 16 + l15] * SC2;
    }

    facc acc[2][4]; facc accq[2];
    #pragma unroll
    for (int i = 0; i < 2; ++i) {
        #pragma unroll
        for (int j = 0; j < 4; ++j) { acc[i][j][0]=0.f; acc[i][j][1]=0.f; acc[i][j][2]=0.f; acc[i][j][3]=0.f; }
        accq[i][0]=0.f; accq[i][1]=0.f; accq[i][2]=0.f; accq[i][3]=0.f;
    }

    if (tid < 128)
        gl2lds16(vq2b + colpair * 1024 + tid * 8, &svq[tid * 8]);

    auto stage = [&](int sel, int k0) {
        unsigned short* dA = smem + sel * 12288;
        unsigned short* dB = dA + 4096;
        #pragma unroll
        for (int it = 0; it < 2; ++it) {
            int g = it * 256 + tid;
            int r = g >> 3, kg = g & 7;
            gl2lds16(A + (size_t)(row0 + r) * 512 + k0 + kg * 8, &dA[g * 8]);
        }
        #pragma unroll
        for (int it = 0; it < 4; ++it) {
            int g = it * 256 + tid;
            int r = g >> 3, kg = g & 7;
            gl2lds16(B + (size_t)(n0 + r) * 512 + k0 + kg * 8, &dB[g * 8]);
        }
    };

    stage(0, 0);
    #pragma unroll
    for (int kt = 0; kt < 8; ++kt) {
        const int sel = kt & 1;
        if (kt < 7) {
            stage(sel ^ 1, (kt + 1) * 64);
            asm volatile("s_waitcnt vmcnt(6)" ::: "memory");
        } else {
            asm volatile("s_waitcnt vmcnt(0)" ::: "memory");
        }
        __builtin_amdgcn_s_barrier();
        __builtin_amdgcn_sched_barrier(0);
        const unsigned short* sA = smem + sel * 12288;
        const unsigned short* sB = sA + 4096;
        #pragma unroll
        for (int ks_ = 0; ks_ < 2; ++ks_) {
            int slot = (ks_ * 4 + quad) ^ (l15 & 7);
            bfrag a[2], b[4];
            #pragma unroll
            for (int i = 0; i < 2; ++i)
                a[i] = *(const bfrag*)&sA[(wr * 32 + i * 16 + l15) * 64 + slot * 8];
            #pragma unroll
            for (int nt = 0; nt < 4; ++nt)
                b[nt] = *(const bfrag*)&sB[(wc * 64 + nt * 16 + l15) * 64 + slot * 8];
            bfrag bvq = *(const bfrag*)&svq[wc * 512 + kt * 64 + ks_ * 32 + quad * 8];
            #pragma unroll
            for (int i = 0; i < 2; ++i) {
                #pragma unroll
                for (int nt = 0; nt < 4; ++nt)
                    acc[i][nt] = __builtin_amdgcn_mfma_f32_16x16x32_bf16(a[i], b[nt], acc[i][nt], 0, 0, 0);
                accq[i] = __builtin_amdgcn_mfma_f32_16x16x32_bf16(a[i], bvq, accq[i], 0, 0, 0);
            }
        }
        __builtin_amdgcn_s_barrier();
        __builtin_amdgcn_sched_barrier(0);
    }
    asm volatile("" ::: "memory");

    // ---- epilogue: bias, qs2/ks2, per-head LDS transpose, coalesced stores ----
    const int bb = row0 >> 10, t0 = row0 & 1023;
    float part[2][4];
    #pragma unroll
    for (int i = 0; i < 2; ++i)
        #pragma unroll
        for (int r = 0; r < 4; ++r) part[i][r] = 0.f;

    unsigned short* eT = smem + wc * 4608;   // per head [64 d][72 t-stride]
    #pragma unroll
    for (int i = 0; i < 2; ++i) {
        int tr = wr * 32 + i * 16 + quad * 4;
        #pragma unroll
        for (int nt = 0; nt < 4; ++nt) {
            int d = nt * 16 + l15;
            float v0 = acc[i][nt][0] + bvv[nt], v1 = acc[i][nt][1] + bvv[nt];
            float v2 = acc[i][nt][2] + bvv[nt], v3 = acc[i][nt][3] + bvv[nt];
            part[i][0] = fmaf(wmv[nt], v0, part[i][0]);
            part[i][1] = fmaf(wmv[nt], v1, part[i][1]);
            part[i][2] = fmaf(wmv[nt], v2, part[i][2]);
            part[i][3] = fmaf(wmv[nt], v3, part[i][3]);
            *(unsigned*)&eT[d * 72 + tr]     = pack2rne(v0, v1);
            *(unsigned*)&eT[d * 72 + tr + 2] = pack2rne(v2, v3);
        }
    }
    #pragma unroll
    for (int i = 0; i < 2; ++i)
        #pragma unroll
        for (int r = 0; r < 4; ++r) {
            float p = part[i][r];
            p += __shfl_xor(p, 1); p += __shfl_xor(p, 2);
            p += __shfl_xor(p, 4); p += __shfl_xor(p, 8);
            if (l15 == 0) {
                size_t o = (size_t)(bb * HH + h) * TT + t0 + wr * 32 + i * 16 + quad * 4 + r;
                ks2[o] = p;
                qs2[o] = accq[i][r] + qsbh;
            }
        }
    __syncthreads();
    #pragma unroll
    for (int it = 0; it < 4; ++it) {
        int task = it * 256 + tid;
        int hh = task >> 9, rem = task & 511;
        int col = rem >> 3, seg = rem & 7;
        uint4 v = *(const uint4*)&smem[hh * 4608 + col * 72 + seg * 8];
        int hg = colpair * 2 + hh;
        int g = (t0 >> 3) + seg;
        int p = g ^ (col & 7);
        *(uint4*)(kxTg + ((size_t)(bb * HH + hg) * 64 + col) * TT + p * 8) = v;
    }
}

// ---- K3a: node-curve partials. grid (64 bh, 4 kq) = 256 blocks. NND=64. -------
__global__ __launch_bounds__(256) void nodes_kernel(
    const unsigned short* __restrict__ kxTg, const float* __restrict__ qs2,
    const float* __restrict__ ks2, float* __restrict__ npart)
{
    __shared__ __align__(16) unsigned short kxT[16384]; // 32 KB
    __shared__ float tks[256];
    __shared__ float redl[8];
    const int bh = blockIdx.x, kq = blockIdx.y;
    const int tid = threadIdx.x, lane = tid & 63, wave = tid >> 6;
    const int l15 = lane & 15, quad = lane >> 4;
    const unsigned short* kxbase = kxTg + (size_t)bh * 64 * TT;

    #pragma unroll
    for (int it = 0; it < 8; ++it) {
        int g = it * 256 + tid;
        int d = g >> 5, j = g & 31;
        gl2lds16(kxbase + (size_t)d * TT + kq * 256 + j * 8, &kxT[g * 8]);
    }
    float ksv = ks2[(size_t)bh * TT + kq * 256 + tid];
    float4 q4 = ((const float4*)(qs2 + (size_t)bh * TT))[tid];
    tks[tid] = __builtin_amdgcn_exp2f(ksv);
    float mn = fminf(fminf(q4.x, q4.y), fminf(q4.z, q4.w));
    float mx = fmaxf(fmaxf(q4.x, q4.y), fmaxf(q4.z, q4.w));
    #pragma unroll
    for (int off = 32; off > 0; off >>= 1) {
        mn = fminf(mn, __shfl_xor(mn, off));
        mx = fmaxf(mx, __shfl_xor(mx, off));
    }
    if (lane == 0) { redl[wave] = mn; redl[4 + wave] = mx; }
    __syncthreads();   // drains stage vmcnt + LDS writes
    const float mnv = fminf(fminf(redl[0], redl[1]), fminf(redl[2], redl[3]));
    const float mxv = fmaxf(fmaxf(redl[4], redl[5]), fmaxf(redl[6], redl[7]));
    const float h2v = (mxv - mnv) * (1.f / 63.f);
    const float z0 = mnv + (wave * 16 + l15) * h2v;    // node = wave*16 + l15
    const float tz = __builtin_amdgcn_exp2f(z0);

    facc acc[4]; facc accZ;
    #pragma unroll
    for (int i = 0; i < 4; ++i) { acc[i][0]=0.f; acc[i][1]=0.f; acc[i][2]=0.f; acc[i][3]=0.f; }
    accZ[0]=0.f; accZ[1]=0.f; accZ[2]=0.f; accZ[3]=0.f;
    bfrag ones;
    #pragma unroll
    for (int j = 0; j < 8; ++j) ones[j] = (short)0x3F80;

    #pragma unroll
    for (int kst = 0; kst < 8; ++kst) {
        const float* kvp = &tks[kst * 32 + quad * 8];
        float4 kv0 = *(const float4*)kvp;
        float4 kv1 = *(const float4*)(kvp + 4);
        int slot = (kst * 4 + quad) ^ (l15 & 7);
        bfrag bf_[4];
        #pragma unroll
        for (int dt = 0; dt < 4; ++dt)
            bf_[dt] = *(const bfrag*)&kxT[(dt * 16 + l15) * 256 + slot * 8];
        union { unsigned u[4]; bfrag f; } afu;
        afu.u[0] = pack2hu(wt(tz * kv0.x), wt(tz * kv0.y));
        afu.u[1] = pack2hu(wt(tz * kv0.z), wt(tz * kv0.w));
        afu.u[2] = pack2hu(wt(tz * kv1.x), wt(tz * kv1.y));
        afu.u[3] = pack2hu(wt(tz * kv1.z), wt(tz * kv1.w));
        #pragma unroll
        for (int dt = 0; dt < 4; ++dt)
            acc[dt] = __builtin_amdgcn_mfma_f32_16x16x32_bf16(afu.f, bf_[dt], acc[dt], 0, 0, 0);
        accZ = __builtin_amdgcn_mfma_f32_16x16x32_bf16(afu.f, ones, accZ, 0, 0, 0);
    }
    float* dst = npart + (size_t)(bh * 4 + kq) * (NND * NS);
    #pragma unroll
    for (int r = 0; r < 4; ++r) {
        int node = wave * 16 + quad * 4 + r;
        #pragma unroll
        for (int dt = 0; dt < 4; ++dt)
            dst[node * NS + dt * 16 + l15] = acc[dt][r];
        if (l15 == 0) dst[node * NS + 64] = accZ[r];
    }
}

// ---- K3b: sum partials + fused cubic interp. grid (64 bh, 4 tq). NND=64. ------
__global__ __launch_bounds__(256) void interp_kernel(
    const float* __restrict__ npart, const float* __restrict__ qs2,
    unsigned short* __restrict__ attb)
{
    __shared__ __align__(16) float nodes[NND * NS];   // 17.4 KB
    __shared__ float redl[8];
    const int bh = blockIdx.x, tq = blockIdx.y;
    const int b = bh >> 3, h = bh & 7;
    const int tid = threadIdx.x, lane = tid & 63, wave = tid >> 6;

    // minmax over qs2 row — ops IDENTICAL to nodes_kernel -> bitwise-same mnv/mxv
    float4 q4 = ((const float4*)(qs2 + (size_t)bh * TT))[tid];
    float mn = fminf(fminf(q4.x, q4.y), fminf(q4.z, q4.w));
    float mx = fmaxf(fmaxf(q4.x, q4.y), fmaxf(q4.z, q4.w));
    #pragma unroll
    for (int off = 32; off > 0; off >>= 1) {
        mn = fminf(mn, __shfl_xor(mn, off));
        mx = fmaxf(mx, __shfl_xor(mx, off));
    }
    if (lane == 0) { redl[wave] = mn; redl[4 + wave] = mx; }
    __syncthreads();
    const float mnv = fminf(fminf(redl[0], redl[1]), fminf(redl[2], redl[3]));
    const float mxv = fmaxf(fmaxf(redl[4], redl[5]), fmaxf(redl[6], redl[7]));
    const float invv = 63.f / fmaxf(mxv - mnv, 1e-12f);

    // sum 4 k-quarter partials (fixed order -> deterministic)
    const float4* p0 = (const float4*)(npart + (size_t)(bh * 4 + 0) * (NND * NS));
    const float4* p1 = (const float4*)(npart + (size_t)(bh * 4 + 1) * (NND * NS));
    const float4* p2 = (const float4*)(npart + (size_t)(bh * 4 + 2) * (NND * NS));
    const float4* p3 = (const float4*)(npart + (size_t)(bh * 4 + 3) * (NND * NS));
    #pragma unroll
    for (int it = 0; it < 5; ++it) {
        int g = it * 256 + tid;
        if (g < (NND * NS) / 4) {
            float4 a = p0[g], bb4 = p1[g], c = p2[g], d = p3[g];
            float4 s;
            s.x = a.x + bb4.x + c.x + d.x;
            s.y = a.y + bb4.y + c.y + d.y;
            s.z = a.z + bb4.z + c.z + d.z;
            s.w = a.w + bb4.w + c.w + d.w;
            ((float4*)nodes)[g] = s;
        }
    }
    __syncthreads();

    const float* qsp = qs2 + (size_t)bh * TT;
    #pragma unroll 2
    for (int it = 0; it < 16; ++it) {
        int task = it * 256 + tid;
        int t = tq * 256 + (task >> 4), dp = task & 15;
        float qv = qsp[t];
        float u = (qv - mnv) * invv;
        int i = (int)floorf(u) - 1;
        i = i < 0 ? 0 : (i > NND - 4 ? NND - 4 : i);
        float s = u - (float)i;
        float s1 = s - 1.f, s2 = s - 2.f, s3 = s - 3.f;
        float w0 = -s1 * s2 * s3 * (1.f / 6.f);
        float w1 = s * s2 * s3 * 0.5f;
        float w2 = -s * s1 * s3 * 0.5f;
        float w3 = s * s1 * s2 * (1.f / 6.f);
        const float* base = &nodes[i * NS];
        float4 v0 = *(const float4*)(base + 4 * dp);
        float4 v1 = *(const float4*)(base + NS + 4 * dp);
        float4 v2 = *(const float4*)(base + 2 * NS + 4 * dp);
        float4 v3 = *(const float4*)(base + 3 * NS + 4 * dp);
        float zz = w0 * base[64] + w1 * base[NS + 64] + w2 * base[2 * NS + 64] + w3 * base[3 * NS + 64];
        float ox = w0 * v0.x + w1 * v1.x + w2 * v2.x + w3 * v3.x;
        float oy = w0 * v0.y + w1 * v1.y + w2 * v2.y + w3 * v3.y;
        float oz = w0 * v0.z + w1 * v1.z + w2 * v2.z + w3 * v3.z;
        float ow = w0 * v0.w + w1 * v1.w + w2 * v2.w + w3 * v3.w;
        float rz = __builtin_amdgcn_rcpf(zz);
        uint2 st;
        st.x = pack2rne(ox * rz, oy * rz);
        st.y = pack2rne(oz * rz, ow * rz);
        int row = b * TT + t;
        int col = h * 64 + 4 * dp;
        int p = (col >> 3) ^ (row & 7);
        *(uint2*)&attb[(size_t)row * DDIM + p * 8 + (col & 7)] = st;
    }
}

// ---- K4: fused GEMM2 + residual + LayerNorm -----------------------------------
// Tile 32 rows x 512 cols (full D -> LN reduction stays in-block). 256 blocks x
// 512 threads (8 waves/CU, same TLP as 2x256 before). B (WpT) dbuf 2x64KB LDS;
// A (attb) fragments prefetched to REGISTERS one K-step ahead so the counted
// vmcnt(12) = 4 a-loads + 8 B-stage loads per step stays exact and uniform.
__global__ __launch_bounds__(512) void gemm2ln_kernel(
    const unsigned short* __restrict__ A, const unsigned short* __restrict__ B,
    const float* __restrict__ bias, const float* __restrict__ x,
    const float* __restrict__ gam, const float* __restrict__ bet,
    float* __restrict__ out)
{
    __shared__ __align__(16) unsigned short sB[2 * 32768];   // 128 KB
    const int tid = threadIdx.x, lane = tid & 63, wave = tid >> 6;
    const int l15 = lane & 15, quad = lane >> 4;
    const int wc = wave;                       // 8 waves x 64 cols
    const int row0 = blockIdx.x * 32;

    float bvv[4], gv[4], btv[4];
    #pragma unroll
    for (int nt = 0; nt < 4; ++nt) {
        int col = wc * 64 + nt * 16 + l15;
        bvv[nt] = bias[col];
        gv[nt]  = gam[col];
        btv[nt] = bet[col];
    }

    facc acc[2][4];
    #pragma unroll
    for (int i = 0; i < 2; ++i)
        #pragma unroll
        for (int j = 0; j < 4; ++j) { acc[i][j][0]=0.f; acc[i][j][1]=0.f; acc[i][j][2]=0.f; acc[i][j][3]=0.f; }

    auto stageB = [&](int sel, int k0) {
        unsigned short* dB = sB + sel * 32768;
        #pragma unroll
        for (int it = 0; it < 8; ++it) {
            int g = it * 512 + tid;
            int r = g >> 3, kg = g & 7;
            gl2lds16(B + (size_t)r * 512 + k0 + kg * 8, &dB[g * 8]);
        }
    };
    auto aload = [&](bfrag (&af)[2][2], int kt) {
        #pragma unroll
        for (int i = 0; i < 2; ++i)
            #pragma unroll
            for (int ks = 0; ks < 2; ++ks) {
                int row = row0 + i * 16 + l15;
                int G = kt * 8 + ks * 4 + quad;
                af[i][ks] = *(const bfrag*)(A + (size_t)row * 512 + (G ^ (l15 & 7)) * 8);
            }
    };

    bfrag aEv[2][2], aOd[2][2];
    aload(aEv, 0);
    stageB(0, 0);
    #pragma unroll
    for (int kt = 0; kt < 8; ++kt) {
        const int sel = kt & 1;
        bfrag (&acur)[2][2] = (kt & 1) ? aOd : aEv;
        bfrag (&anxt)[2][2] = (kt & 1) ? aEv : aOd;
        if (kt < 7) {
            aload(anxt, kt + 1);
            stageB(sel ^ 1, (kt + 1) * 64);
            asm volatile("s_waitcnt vmcnt(12)" ::: "memory");
        } else {
            asm volatile("s_waitcnt vmcnt(0)" ::: "memory");
        }
        __builtin_amdgcn_s_barrier();
        __builtin_amdgcn_sched_barrier(0);
        const unsigned short* sb = sB + sel * 32768;
        #pragma unroll
        for (int ks = 0; ks < 2; ++ks) {
            int slot = (ks * 4 + quad) ^ (l15 & 7);
            #pragma unroll
            for (int nt = 0; nt < 4; ++nt) {
                bfrag bf = *(const bfrag*)&sb[(wc * 64 + nt * 16 + l15) * 64 + slot * 8];
                #pragma unroll
                for (int i = 0; i < 2; ++i)
                    acc[i][nt] = __builtin_amdgcn_mfma_f32_16x16x32_bf16(acur[i][ks], bf, acc[i][nt], 0, 0, 0);
            }
        }
        __builtin_amdgcn_s_barrier();
        __builtin_amdgcn_sched_barrier(0);
    }
    asm volatile("" ::: "memory");
    __syncthreads();                    // LDS now reusable for LN exchange

    float* sred  = (float*)sB;          // [32][8]
    float* s2red = (float*)sB + 256;    // [32][8]
    float* mv    = (float*)sB + 512;    // [32][2]

    // y = proj + bias + x (f32, exact residual)
    float yv[2][4][4];
    #pragma unroll
    for (int i = 0; i < 2; ++i)
        #pragma unroll
        for (int nt = 0; nt < 4; ++nt) {
            int col = wc * 64 + nt * 16 + l15;
            #pragma unroll
            for (int r = 0; r < 4; ++r) {
                int row = row0 + i * 16 + quad * 4 + r;
                yv[i][nt][r] = acc[i][nt][r] + bvv[nt] + x[(size_t)row * 512 + col];
            }
        }
    // row sums over this wave's 64 cols, then cross-wave via LDS
    #pragma unroll
    for (int i = 0; i < 2; ++i)
        #pragma unroll
        for (int r = 0; r < 4; ++r) {
            float s = 0.f, s2 = 0.f;
            #pragma unroll
            for (int nt = 0; nt < 4; ++nt) {
                s += yv[i][nt][r];
                s2 = fmaf(yv[i][nt][r], yv[i][nt][r], s2);
            }
            s  += __shfl_xor(s, 1);  s  += __shfl_xor(s, 2);
            s  += __shfl_xor(s, 4);  s  += __shfl_xor(s, 8);
            s2 += __shfl_xor(s2, 1); s2 += __shfl_xor(s2, 2);
            s2 += __shfl_xor(s2, 4); s2 += __shfl_xor(s2, 8);
            if (l15 == 0) {
                int rr = i * 16 + quad * 4 + r;
                sred[rr * 8 + wc]  = s;
                s2red[rr * 8 + wc] = s2;
            }
        }
    __syncthreads();
    if (tid < 32) {
        float s = 0.f, s2 = 0.f;
        #pragma unroll
        for (int w = 0; w < 8; ++w) { s += sred[tid * 8 + w]; s2 += s2red[tid * 8 + w]; }
        float mu = s * (1.f / 512.f);
        float var = s2 * (1.f / 512.f) - mu * mu;
        mv[tid * 2]     = mu;
        mv[tid * 2 + 1] = rsqrtf(var + 1e-5f);
    }
    __syncthreads();
    #pragma unroll
    for (int i = 0; i < 2; ++i)
        #pragma unroll
        for (int r = 0; r < 4; ++r) {
            int rr = i * 16 + quad * 4 + r;
            float mu = mv[rr * 2], inv = mv[rr * 2 + 1];
            #pragma unroll
            for (int nt = 0; nt < 4; ++nt) {
                int col = wc * 64 + nt * 16 + l15;
                out[(size_t)(row0 + rr) * 512 + col] = (yv[i][nt][r] - mu) * inv * gv[nt] + btv[nt];
            }
        }
}

// ---- launch -------------------------------------------------------------------
extern "C" void kernel_launch(void* const* d_in, const int* in_sizes, int n_in,
                              void* d_out, int out_size, void* d_ws, size_t ws_size,
                              hipStream_t stream)
{
    const float* x    = (const float*)d_in[0];
    const float* Wq   = (const float*)d_in[1];
    const float* bq   = (const float*)d_in[2];
    const float* Wk   = (const float*)d_in[3];
    const float* bk   = (const float*)d_in[4];
    const float* Wp   = (const float*)d_in[5];
    const float* bp   = (const float*)d_in[6];
    const float* wm   = (const float*)d_in[7];
    const float* ln_g = (const float*)d_in[8];
    const float* ln_b = (const float*)d_in[9];
    float* out = (float*)d_out;

    float* ws = (float*)d_ws;
    float*          qsb2 = ws;                                    // 64
    unsigned short* vq2b = (unsigned short*)(ws + 64);            // 2048 f
    unsigned short* WkT  = (unsigned short*)(ws + 2112);          // 131072 f
    unsigned short* WpT  = (unsigned short*)(ws + 133184);        // 131072 f
    unsigned short* xb   = (unsigned short*)(ws + 264256);        // 2097152 f
    unsigned short* kxTg = (unsigned short*)(ws + 2361408);       // 2097152 f
    float*          qs2  = ws + 4458560;                          // 65536
    float*          ks2  = ws + 4524096;                          // 65536
    unsigned short* attb = (unsigned short*)(ws + 4589632);       // 2097152 f
    float*          npart = ws + 8783936;                         // 64*4*64*68 = 1114112 f

    prepare_kernel<<<3200, 256, 0, stream>>>(x, Wk, Wp, Wq, bq, wm,
                                             xb, WkT, WpT, vq2b, qsb2);
    gemm1_kernel<<<dim3(128, 4), 256, 0, stream>>>(xb, WkT, bk, kxTg, ks2, wm,
                                                   vq2b, qsb2, qs2);
    nodes_kernel<<<dim3(64, 4), 256, 0, stream>>>(kxTg, qs2, ks2, npart);
    interp_kernel<<<dim3(64, 4), 256, 0, stream>>>(npart, qs2, attb);
    gemm2ln_kernel<<<256, 512, 0, stream>>>(attb, WpT, bp, x, ln_g, ln_b, out);
}

// Round 9
// 128.410 us; speedup vs baseline: 1.0021x; 1.0021x over previous
//
#include <hip/hip_runtime.h>
#include <cstddef>

#define TT 1024
#define DDIM 512
#define HH 8
#define NND 64           // interpolation nodes per (b,h): h^4 cubic error ~6e-5, safe
#define NS 68            // node row stride (floats): 64 d + Z at [64]

typedef __attribute__((ext_vector_type(8))) short bfrag;   // 8 bf16 (4 VGPRs)
typedef __attribute__((ext_vector_type(4))) float facc;    // 4 fp32 acc

#define SC2   2.8853900817779268f   // 2*log2(e)
#define L2E   1.4426950408889634f

static __device__ __forceinline__ unsigned bfrne(float f) {
    unsigned u = __float_as_uint(f);
    return (u + 0x7fffu + ((u >> 16) & 1u)) >> 16;
}
static __device__ __forceinline__ unsigned pack2rne(float a, float b) {
    return bfrne(a) | (bfrne(b) << 16);
}
static __device__ __forceinline__ unsigned pack2hu(float a, float b) {
    return ((__float_as_uint(a) + 0x8000u) >> 16) |
           ((__float_as_uint(b) + 0x8000u) & 0xffff0000u);
}
static __device__ __forceinline__ void gl2lds16(const void* g, void* l) {
    __builtin_amdgcn_global_load_lds(
        (const __attribute__((address_space(1))) unsigned int*)g,
        (__attribute__((address_space(3))) unsigned int*)l, 16, 0, 0);
}
// w from pre-multiplied t = exp2(z2_node)*exp2(kv2):  w = exp(tanh(z)) = e^{1-2/(t+1)}
static __device__ __forceinline__ float wt(float t) {
    float r = __builtin_amdgcn_rcpf(t + 1.f);
    return __builtin_amdgcn_exp2f(fmaf(r, -2.f * L2E, L2E));
}

// ---- K1: fused prepare ---------------------------------------------------------
__global__ __launch_bounds__(256) void prepare_kernel(
    const float* __restrict__ x, const float* __restrict__ Wk,
    const float* __restrict__ Wp, const float* __restrict__ Wq,
    const float* __restrict__ bq, const float* __restrict__ wm,
    unsigned short* __restrict__ xb, unsigned short* __restrict__ WkT,
    unsigned short* __restrict__ WpT, unsigned short* __restrict__ vq2b,
    float* __restrict__ qsb2)
{
    const int bx = blockIdx.x, tid = threadIdx.x;
    const int lane = tid & 63, wave = tid >> 6;
    if (bx < 2048) {
        const int row = bx * 4 + wave;
        const float4* xr = (const float4*)(x + (size_t)row * DDIM);
        float4 x0 = xr[lane * 2], x1 = xr[lane * 2 + 1];
        uint4 st;
        st.x = pack2rne(x0.x, x0.y); st.y = pack2rne(x0.z, x0.w);
        st.z = pack2rne(x1.x, x1.y); st.w = pack2rne(x1.z, x1.w);
        int p = lane ^ (row & 7);
        *(uint4*)(xb + (size_t)row * DDIM + p * 8) = st;
    } else if (bx < 2176) {
        int idx = bx - 2048;
        const float* src = (idx & 64) ? Wp : Wk;
        unsigned short* dst = (idx & 64) ? WpT : WkT;
        idx &= 63;
        const int n0 = (idx & 7) * 64, k0 = (idx >> 3) * 64;
        __shared__ float sT[64][65];
        #pragma unroll
        for (int it = 0; it < 4; ++it) {
            int task = it * 256 + tid;
            int kr = task >> 4, c4 = (task & 15) * 4;
            float4 v = *(const float4*)(src + (size_t)(k0 + kr) * DDIM + n0 + c4);
            sT[kr][c4] = v.x; sT[kr][c4 + 1] = v.y; sT[kr][c4 + 2] = v.z; sT[kr][c4 + 3] = v.w;
        }
        __syncthreads();
        #pragma unroll
        for (int it = 0; it < 2; ++it) {
            int task = it * 256 + tid;
            int n = task >> 3, kg = task & 7;
            unsigned u[4];
            #pragma unroll
            for (int jj = 0; jj < 4; ++jj)
                u[jj] = pack2rne(sT[kg * 8 + jj * 2][n], sT[kg * 8 + jj * 2 + 1][n]);
            int p = ((k0 >> 3) + kg) ^ (n & 7);
            uint4 st; st.x = u[0]; st.y = u[1]; st.z = u[2]; st.w = u[3];
            *(uint4*)(dst + (size_t)(n0 + n) * DDIM + p * 8) = st;
        }
    } else {
        int idx = (bx - 2176) * 4 + wave;   // 0..4095
        int h = idx >> 9, d = idx & 511;
        float v = Wq[(size_t)d * DDIM + h * 64 + lane] * wm[64 + lane];
        #pragma unroll
        for (int off = 32; off > 0; off >>= 1) v += __shfl_xor(v, off);
        if (lane == 0) vq2b[h * DDIM + d] = (unsigned short)bfrne(v * SC2);
        if (bx == 2176 && tid < HH) {
            float sb = 0.f;
            for (int j = 0; j < 64; ++j)
                sb = fmaf(bq[tid * 64 + j], wm[64 + j], sb);
            qsb2[tid] = sb * SC2;
        }
    }
}

// ---- K2: GEMM1 kx = xb @ WkT + bk. Tile 64 t x 128 n, grid 512 = 2 blocks/CU. --
__global__ __launch_bounds__(256) void gemm1_kernel(
    const unsigned short* __restrict__ A, const unsigned short* __restrict__ B,
    const float* __restrict__ bias, unsigned short* __restrict__ kxTg,
    float* __restrict__ ks2, const float* __restrict__ wm,
    const unsigned short* __restrict__ vq2b, const float* __restrict__ qsb2,
    float* __restrict__ qs2)
{
    // 2 bufs x (A 4096 | B 8192) = 24576 shorts + svq 1024; epi eT 2x4608 reuses buf0
    __shared__ __align__(16) unsigned short smem[25600];
    unsigned short* svq = smem + 24576;
    const int tid = threadIdx.x, lane = tid & 63, wave = tid >> 6;
    const int l15 = lane & 15, quad = lane >> 4;
    const int wr = wave >> 1, wc = wave & 1;           // 2x2 wave grid: 32 rows x 64 cols
    const int row0 = blockIdx.x * 64, colpair = blockIdx.y;
    const int h = colpair * 2 + wc, n0 = colpair * 128;

    const float qsbh = qsb2[h];
    float bvv[4], wmv[4];
    #pragma unroll
    for (int nt = 0; nt < 4; ++nt) {
        bvv[nt] = bias[h * 64 + nt * 16 + l15];
        wmv[nt] = wm[nt * 16 + l15] * SC2;
    }

    facc acc[2][4]; facc accq[2];
    #pragma unroll
    for (int i = 0; i < 2; ++i) {
        #pragma unroll
        for (int j = 0; j < 4; ++j) { acc[i][j][0]=0.f; acc[i][j][1]=0.f; acc[i][j][2]=0.f; acc[i][j][3]=0.f; }
        accq[i][0]=0.f; accq[i][1]=0.f; accq[i][2]=0.f; accq[i][3]=0.f;
    }

    if (tid < 128)
        gl2lds16(vq2b + colpair * 1024 + tid * 8, &svq[tid * 8]);

    auto stage = [&](int sel, int k0) {
        unsigned short* dA = smem + sel * 12288;
        unsigned short* dB = dA + 4096;
        #pragma unroll
        for (int it = 0; it < 2; ++it) {
            int g = it * 256 + tid;
            int r = g >> 3, kg = g & 7;
            gl2lds16(A + (size_t)(row0 + r) * 512 + k0 + kg * 8, &dA[g * 8]);
        }
        #pragma unroll
        for (int it = 0; it < 4; ++it) {
            int g = it * 256 + tid;
            int r = g >> 3, kg = g & 7;
            gl2lds16(B + (size_t)(n0 + r) * 512 + k0 + kg * 8, &dB[g * 8]);
        }
    };

    stage(0, 0);
    #pragma unroll
    for (int kt = 0; kt < 8; ++kt) {
        const int sel = kt & 1;
        if (kt < 7) {
            stage(sel ^ 1, (kt + 1) * 64);
            asm volatile("s_waitcnt vmcnt(6)" ::: "memory");
        } else {
            asm volatile("s_waitcnt vmcnt(0)" ::: "memory");
        }
        __builtin_amdgcn_s_barrier();
        __builtin_amdgcn_sched_barrier(0);
        const unsigned short* sA = smem + sel * 12288;
        const unsigned short* sB = sA + 4096;
        #pragma unroll
        for (int ks_ = 0; ks_ < 2; ++ks_) {
            int slot = (ks_ * 4 + quad) ^ (l15 & 7);
            bfrag a[2], b[4];
            #pragma unroll
            for (int i = 0; i < 2; ++i)
                a[i] = *(const bfrag*)&sA[(wr * 32 + i * 16 + l15) * 64 + slot * 8];
            #pragma unroll
            for (int nt = 0; nt < 4; ++nt)
                b[nt] = *(const bfrag*)&sB[(wc * 64 + nt * 16 + l15) * 64 + slot * 8];
            bfrag bvq = *(const bfrag*)&svq[wc * 512 + kt * 64 + ks_ * 32 + quad * 8];
            #pragma unroll
            for (int i = 0; i < 2; ++i) {
                #pragma unroll
                for (int nt = 0; nt < 4; ++nt)
                    acc[i][nt] = __builtin_amdgcn_mfma_f32_16x16x32_bf16(a[i], b[nt], acc[i][nt], 0, 0, 0);
                accq[i] = __builtin_amdgcn_mfma_f32_16x16x32_bf16(a[i], bvq, accq[i], 0, 0, 0);
            }
        }
        __builtin_amdgcn_s_barrier();
        __builtin_amdgcn_sched_barrier(0);
    }
    asm volatile("" ::: "memory");

    // ---- epilogue: bias, qs2/ks2, per-head LDS transpose, coalesced stores ----
    const int bb = row0 >> 10, t0 = row0 & 1023;
    float part[2][4];
    #pragma unroll
    for (int i = 0; i < 2; ++i)
        #pragma unroll
        for (int r = 0; r < 4; ++r) part[i][r] = 0.f;

    unsigned short* eT = smem + wc * 4608;   // per head [64 d][72 t-stride]
    #pragma unroll
    for (int i = 0; i < 2; ++i) {
        int tr = wr * 32 + i * 16 + quad * 4;
        #pragma unroll
        for (int nt = 0; nt < 4; ++nt) {
            int d = nt * 16 + l15;
            float v0 = acc[i][nt][0] + bvv[nt], v1 = acc[i][nt][1] + bvv[nt];
            float v2 = acc[i][nt][2] + bvv[nt], v3 = acc[i][nt][3] + bvv[nt];
            part[i][0] = fmaf(wmv[nt], v0, part[i][0]);
            part[i][1] = fmaf(wmv[nt], v1, part[i][1]);
            part[i][2] = fmaf(wmv[nt], v2, part[i][2]);
            part[i][3] = fmaf(wmv[nt], v3, part[i][3]);
            *(unsigned*)&eT[d * 72 + tr]     = pack2rne(v0, v1);
            *(unsigned*)&eT[d * 72 + tr + 2] = pack2rne(v2, v3);
        }
    }
    #pragma unroll
    for (int i = 0; i < 2; ++i)
        #pragma unroll
        for (int r = 0; r < 4; ++r) {
            float p = part[i][r];
            p += __shfl_xor(p, 1); p += __shfl_xor(p, 2);
            p += __shfl_xor(p, 4); p += __shfl_xor(p, 8);
            if (l15 == 0) {
                size_t o = (size_t)(bb * HH + h) * TT + t0 + wr * 32 + i * 16 + quad * 4 + r;
                ks2[o] = p;
                qs2[o] = accq[i][r] + qsbh;
            }
        }
    __syncthreads();
    #pragma unroll
    for (int it = 0; it < 4; ++it) {
        int task = it * 256 + tid;
        int hh = task >> 9, rem = task & 511;
        int col = rem >> 3, seg = rem & 7;
        uint4 v = *(const uint4*)&smem[hh * 4608 + col * 72 + seg * 8];
        int hg = colpair * 2 + hh;
        int g = (t0 >> 3) + seg;
        int p = g ^ (col & 7);
        *(uint4*)(kxTg + ((size_t)(bb * HH + hg) * 64 + col) * TT + p * 8) = v;
    }
}

// ---- K3a: node-curve partials. grid (64 bh, 4 kq) = 256 blocks. NND=64. -------
__global__ __launch_bounds__(256) void nodes_kernel(
    const unsigned short* __restrict__ kxTg, const float* __restrict__ qs2,
    const float* __restrict__ ks2, float* __restrict__ npart)
{
    __shared__ __align__(16) unsigned short kxT[16384]; // 32 KB
    __shared__ float tks[256];
    __shared__ float redl[8];
    const int bh = blockIdx.x, kq = blockIdx.y;
    const int tid = threadIdx.x, lane = tid & 63, wave = tid >> 6;
    const int l15 = lane & 15, quad = lane >> 4;
    const unsigned short* kxbase = kxTg + (size_t)bh * 64 * TT;

    #pragma unroll
    for (int it = 0; it < 8; ++it) {
        int g = it * 256 + tid;
        int d = g >> 5, j = g & 31;
        gl2lds16(kxbase + (size_t)d * TT + kq * 256 + j * 8, &kxT[g * 8]);
    }
    float ksv = ks2[(size_t)bh * TT + kq * 256 + tid];
    float4 q4 = ((const float4*)(qs2 + (size_t)bh * TT))[tid];
    tks[tid] = __builtin_amdgcn_exp2f(ksv);
    float mn = fminf(fminf(q4.x, q4.y), fminf(q4.z, q4.w));
    float mx = fmaxf(fmaxf(q4.x, q4.y), fmaxf(q4.z, q4.w));
    #pragma unroll
    for (int off = 32; off > 0; off >>= 1) {
        mn = fminf(mn, __shfl_xor(mn, off));
        mx = fmaxf(mx, __shfl_xor(mx, off));
    }
    if (lane == 0) { redl[wave] = mn; redl[4 + wave] = mx; }
    __syncthreads();   // drains stage vmcnt + LDS writes
    const float mnv = fminf(fminf(redl[0], redl[1]), fminf(redl[2], redl[3]));
    const float mxv = fmaxf(fmaxf(redl[4], redl[5]), fmaxf(redl[6], redl[7]));
    const float h2v = (mxv - mnv) * (1.f / 63.f);
    const float z0 = mnv + (wave * 16 + l15) * h2v;    // node = wave*16 + l15
    const float tz = __builtin_amdgcn_exp2f(z0);

    facc acc[4]; facc accZ;
    #pragma unroll
    for (int i = 0; i < 4; ++i) { acc[i][0]=0.f; acc[i][1]=0.f; acc[i][2]=0.f; acc[i][3]=0.f; }
    accZ[0]=0.f; accZ[1]=0.f; accZ[2]=0.f; accZ[3]=0.f;
    bfrag ones;
    #pragma unroll
    for (int j = 0; j < 8; ++j) ones[j] = (short)0x3F80;

    #pragma unroll
    for (int kst = 0; kst < 8; ++kst) {
        const float* kvp = &tks[kst * 32 + quad * 8];
        float4 kv0 = *(const float4*)kvp;
        float4 kv1 = *(const float4*)(kvp + 4);
        int slot = (kst * 4 + quad) ^ (l15 & 7);
        bfrag bf_[4];
        #pragma unroll
        for (int dt = 0; dt < 4; ++dt)
            bf_[dt] = *(const bfrag*)&kxT[(dt * 16 + l15) * 256 + slot * 8];
        union { unsigned u[4]; bfrag f; } afu;
        afu.u[0] = pack2hu(wt(tz * kv0.x), wt(tz * kv0.y));
        afu.u[1] = pack2hu(wt(tz * kv0.z), wt(tz * kv0.w));
        afu.u[2] = pack2hu(wt(tz * kv1.x), wt(tz * kv1.y));
        afu.u[3] = pack2hu(wt(tz * kv1.z), wt(tz * kv1.w));
        #pragma unroll
        for (int dt = 0; dt < 4; ++dt)
            acc[dt] = __builtin_amdgcn_mfma_f32_16x16x32_bf16(afu.f, bf_[dt], acc[dt], 0, 0, 0);
        accZ = __builtin_amdgcn_mfma_f32_16x16x32_bf16(afu.f, ones, accZ, 0, 0, 0);
    }
    float* dst = npart + (size_t)(bh * 4 + kq) * (NND * NS);
    #pragma unroll
    for (int r = 0; r < 4; ++r) {
        int node = wave * 16 + quad * 4 + r;
        #pragma unroll
        for (int dt = 0; dt < 4; ++dt)
            dst[node * NS + dt * 16 + l15] = acc[dt][r];
        if (l15 == 0) dst[node * NS + 64] = accZ[r];
    }
}

// ---- K3b: sum partials + fused cubic interp. grid (64 bh, 4 tq). NND=64. ------
__global__ __launch_bounds__(256) void interp_kernel(
    const float* __restrict__ npart, const float* __restrict__ qs2,
    unsigned short* __restrict__ attb)
{
    __shared__ __align__(16) float nodes[NND * NS];   // 17.4 KB
    __shared__ float redl[8];
    const int bh = blockIdx.x, tq = blockIdx.y;
    const int b = bh >> 3, h = bh & 7;
    const int tid = threadIdx.x, lane = tid & 63, wave = tid >> 6;

    // minmax over qs2 row — ops IDENTICAL to nodes_kernel -> bitwise-same mnv/mxv
    float4 q4 = ((const float4*)(qs2 + (size_t)bh * TT))[tid];
    float mn = fminf(fminf(q4.x, q4.y), fminf(q4.z, q4.w));
    float mx = fmaxf(fmaxf(q4.x, q4.y), fmaxf(q4.z, q4.w));
    #pragma unroll
    for (int off = 32; off > 0; off >>= 1) {
        mn = fminf(mn, __shfl_xor(mn, off));
        mx = fmaxf(mx, __shfl_xor(mx, off));
    }
    if (lane == 0) { redl[wave] = mn; redl[4 + wave] = mx; }
    __syncthreads();
    const float mnv = fminf(fminf(redl[0], redl[1]), fminf(redl[2], redl[3]));
    const float mxv = fmaxf(fmaxf(redl[4], redl[5]), fmaxf(redl[6], redl[7]));
    const float invv = 63.f / fmaxf(mxv - mnv, 1e-12f);

    // sum 4 k-quarter partials (fixed order -> deterministic)
    const float4* p0 = (const float4*)(npart + (size_t)(bh * 4 + 0) * (NND * NS));
    const float4* p1 = (const float4*)(npart + (size_t)(bh * 4 + 1) * (NND * NS));
    const float4* p2 = (const float4*)(npart + (size_t)(bh * 4 + 2) * (NND * NS));
    const float4* p3 = (const float4*)(npart + (size_t)(bh * 4 + 3) * (NND * NS));
    #pragma unroll
    for (int it = 0; it < 5; ++it) {
        int g = it * 256 + tid;
        if (g < (NND * NS) / 4) {
            float4 a = p0[g], bb4 = p1[g], c = p2[g], d = p3[g];
            float4 s;
            s.x = a.x + bb4.x + c.x + d.x;
            s.y = a.y + bb4.y + c.y + d.y;
            s.z = a.z + bb4.z + c.z + d.z;
            s.w = a.w + bb4.w + c.w + d.w;
            ((float4*)nodes)[g] = s;
        }
    }
    __syncthreads();

    const float* qsp = qs2 + (size_t)bh * TT;
    #pragma unroll 2
    for (int it = 0; it < 16; ++it) {
        int task = it * 256 + tid;
        int t = tq * 256 + (task >> 4), dp = task & 15;
        float qv = qsp[t];
        float u = (qv - mnv) * invv;
        int i = (int)floorf(u) - 1;
        i = i < 0 ? 0 : (i > NND - 4 ? NND - 4 : i);
        float s = u - (float)i;
        float s1 = s - 1.f, s2 = s - 2.f, s3 = s - 3.f;
        float w0 = -s1 * s2 * s3 * (1.f / 6.f);
        float w1 = s * s2 * s3 * 0.5f;
        float w2 = -s * s1 * s3 * 0.5f;
        float w3 = s * s1 * s2 * (1.f / 6.f);
        const float* base = &nodes[i * NS];
        float4 v0 = *(const float4*)(base + 4 * dp);
        float4 v1 = *(const float4*)(base + NS + 4 * dp);
        float4 v2 = *(const float4*)(base + 2 * NS + 4 * dp);
        float4 v3 = *(const float4*)(base + 3 * NS + 4 * dp);
        float zz = w0 * base[64] + w1 * base[NS + 64] + w2 * base[2 * NS + 64] + w3 * base[3 * NS + 64];
        float ox = w0 * v0.x + w1 * v1.x + w2 * v2.x + w3 * v3.x;
        float oy = w0 * v0.y + w1 * v1.y + w2 * v2.y + w3 * v3.y;
        float oz = w0 * v0.z + w1 * v1.z + w2 * v2.z + w3 * v3.z;
        float ow = w0 * v0.w + w1 * v1.w + w2 * v2.w + w3 * v3.w;
        float rz = __builtin_amdgcn_rcpf(zz);
        uint2 st;
        st.x = pack2rne(ox * rz, oy * rz);
        st.y = pack2rne(oz * rz, ow * rz);
        int row = b * TT + t;
        int col = h * 64 + 4 * dp;
        int p = (col >> 3) ^ (row & 7);
        *(uint2*)&attb[(size_t)row * DDIM + p * 8 + (col & 7)] = st;
    }
}

// ---- K4: fused GEMM2 + residual + LayerNorm, BARRIER-FREE ---------------------
// Tile 32 rows x 512 cols (full D -> LN in-block). 256 blocks x 512 threads.
// B (WpT, 512 KB, L2-resident) read DIRECTLY from L2 per MFMA fragment — for a
// fixed (col, granule) the 4 quads read the 4x16B chunks of ONE 64B line, so
// lines are fully utilized. No LDS staging, no barriers in the K-loop; 8 waves
// (2/SIMD) + 8 independent acc chains hide L2 latency (~200cy).
__global__ __launch_bounds__(512) void gemm2ln_kernel(
    const unsigned short* __restrict__ A, const unsigned short* __restrict__ B,
    const float* __restrict__ bias, const float* __restrict__ x,
    const float* __restrict__ gam, const float* __restrict__ bet,
    float* __restrict__ out)
{
    __shared__ float sred[256];    // [32 rows][8 waves]
    __shared__ float s2red[256];
    __shared__ float mv[64];       // [32 rows][mu, rsig]
    const int tid = threadIdx.x, lane = tid & 63, wave = tid >> 6;
    const int l15 = lane & 15, quad = lane >> 4;
    const int wc = wave;                       // 8 waves x 64 cols
    const int row0 = blockIdx.x * 32;

    float bvv[4], gv[4], btv[4];
    #pragma unroll
    for (int nt = 0; nt < 4; ++nt) {
        int col = wc * 64 + nt * 16 + l15;
        bvv[nt] = bias[col];
        gv[nt]  = gam[col];
        btv[nt] = bet[col];
    }

    facc acc[2][4];
    #pragma unroll
    for (int i = 0; i < 2; ++i)
        #pragma unroll
        for (int j = 0; j < 4; ++j) { acc[i][j][0]=0.f; acc[i][j][1]=0.f; acc[i][j][2]=0.f; acc[i][j][3]=0.f; }

    // precomputed per-lane bases: unswizzle XOR is l15&7 for both A and B
    const unsigned short* Abase0 = A + (size_t)(row0 + l15) * 512;
    const unsigned short* Abase1 = A + (size_t)(row0 + 16 + l15) * 512;
    const unsigned short* Bb[4];
    #pragma unroll
    for (int nt = 0; nt < 4; ++nt)
        Bb[nt] = B + (size_t)(wc * 64 + nt * 16 + l15) * 512;
    const int xr = l15 & 7;

    #pragma unroll
    for (int kt = 0; kt < 8; ++kt) {
        #pragma unroll
        for (int ks = 0; ks < 2; ++ks) {
            const int G = kt * 8 + ks * 4 + quad;
            const int gx = (G ^ xr) * 8;
            bfrag a0 = *(const bfrag*)(Abase0 + gx);
            bfrag a1 = *(const bfrag*)(Abase1 + gx);
            bfrag b0 = *(const bfrag*)(Bb[0] + gx);
            bfrag b1 = *(const bfrag*)(Bb[1] + gx);
            bfrag b2 = *(const bfrag*)(Bb[2] + gx);
            bfrag b3 = *(const bfrag*)(Bb[3] + gx);
            acc[0][0] = __builtin_amdgcn_mfma_f32_16x16x32_bf16(a0, b0, acc[0][0], 0, 0, 0);
            acc[0][1] = __builtin_amdgcn_mfma_f32_16x16x32_bf16(a0, b1, acc[0][1], 0, 0, 0);
            acc[0][2] = __builtin_amdgcn_mfma_f32_16x16x32_bf16(a0, b2, acc[0][2], 0, 0, 0);
            acc[0][3] = __builtin_amdgcn_mfma_f32_16x16x32_bf16(a0, b3, acc[0][3], 0, 0, 0);
            acc[1][0] = __builtin_amdgcn_mfma_f32_16x16x32_bf16(a1, b0, acc[1][0], 0, 0, 0);
            acc[1][1] = __builtin_amdgcn_mfma_f32_16x16x32_bf16(a1, b1, acc[1][1], 0, 0, 0);
            acc[1][2] = __builtin_amdgcn_mfma_f32_16x16x32_bf16(a1, b2, acc[1][2], 0, 0, 0);
            acc[1][3] = __builtin_amdgcn_mfma_f32_16x16x32_bf16(a1, b3, acc[1][3], 0, 0, 0);
        }
    }

    // y = proj + bias + x (f32 exact residual)
    float yv[2][4][4];
    #pragma unroll
    for (int i = 0; i < 2; ++i)
        #pragma unroll
        for (int nt = 0; nt < 4; ++nt) {
            int col = wc * 64 + nt * 16 + l15;
            #pragma unroll
            for (int r = 0; r < 4; ++r) {
                int row = row0 + i * 16 + quad * 4 + r;
                yv[i][nt][r] = acc[i][nt][r] + bvv[nt] + x[(size_t)row * 512 + col];
            }
        }
    // row sums over this wave's 64 cols, then cross-wave via LDS
    #pragma unroll
    for (int i = 0; i < 2; ++i)
        #pragma unroll
        for (int r = 0; r < 4; ++r) {
            float s = 0.f, s2 = 0.f;
            #pragma unroll
            for (int nt = 0; nt < 4; ++nt) {
                s += yv[i][nt][r];
                s2 = fmaf(yv[i][nt][r], yv[i][nt][r], s2);
            }
            s  += __shfl_xor(s, 1);  s  += __shfl_xor(s, 2);
            s  += __shfl_xor(s, 4);  s  += __shfl_xor(s, 8);
            s2 += __shfl_xor(s2, 1); s2 += __shfl_xor(s2, 2);
            s2 += __shfl_xor(s2, 4); s2 += __shfl_xor(s2, 8);
            if (l15 == 0) {
                int rr = i * 16 + quad * 4 + r;
                sred[rr * 8 + wc]  = s;
                s2red[rr * 8 + wc] = s2;
            }
        }
    __syncthreads();
    if (tid < 32) {
        float s = 0.f, s2 = 0.f;
        #pragma unroll
        for (int w = 0; w < 8; ++w) { s += sred[tid * 8 + w]; s2 += s2red[tid * 8 + w]; }
        float mu = s * (1.f / 512.f);
        float var = s2 * (1.f / 512.f) - mu * mu;
        mv[tid * 2]     = mu;
        mv[tid * 2 + 1] = rsqrtf(var + 1e-5f);
    }
    __syncthreads();
    #pragma unroll
    for (int i = 0; i < 2; ++i)
        #pragma unroll
        for (int r = 0; r < 4; ++r) {
            int rr = i * 16 + quad * 4 + r;
            float mu = mv[rr * 2], inv = mv[rr * 2 + 1];
            #pragma unroll
            for (int nt = 0; nt < 4; ++nt) {
                int col = wc * 64 + nt * 16 + l15;
                out[(size_t)(row0 + rr) * 512 + col] = (yv[i][nt][r] - mu) * inv * gv[nt] + btv[nt];
            }
        }
}

// ---- launch -------------------------------------------------------------------
extern "C" void kernel_launch(void* const* d_in, const int* in_sizes, int n_in,
                              void* d_out, int out_size, void* d_ws, size_t ws_size,
                              hipStream_t stream)
{
    const float* x    = (const float*)d_in[0];
    const float* Wq   = (const float*)d_in[1];
    const float* bq   = (const float*)d_in[2];
    const float* Wk   = (const float*)d_in[3];
    const float* bk   = (const float*)d_in[4];
    const float* Wp   = (const float*)d_in[5];
    const float* bp   = (const float*)d_in[6];
    const float* wm   = (const float*)d_in[7];
    const float* ln_g = (const float*)d_in[8];
    const float* ln_b = (const float*)d_in[9];
    float* out = (float*)d_out;

    float* ws = (float*)d_ws;
    float*          qsb2 = ws;                                    // 64
    unsigned short* vq2b = (unsigned short*)(ws + 64);            // 2048 f
    unsigned short* WkT  = (unsigned short*)(ws + 2112);          // 131072 f
    unsigned short* WpT  = (unsigned short*)(ws + 133184);        // 131072 f
    unsigned short* xb   = (unsigned short*)(ws + 264256);        // 2097152 f
    unsigned short* kxTg = (unsigned short*)(ws + 2361408);       // 2097152 f
    float*          qs2  = ws + 4458560;                          // 65536
    float*          ks2  = ws + 4524096;                          // 65536
    unsigned short* attb = (unsigned short*)(ws + 4589632);       // 2097152 f
    float*          npart = ws + 8783936;                         // 64*4*64*68 = 1114112 f

    prepare_kernel<<<3200, 256, 0, stream>>>(x, Wk, Wp, Wq, bq, wm,
                                             xb, WkT, WpT, vq2b, qsb2);
    gemm1_kernel<<<dim3(128, 4), 256, 0, stream>>>(xb, WkT, bk, kxTg, ks2, wm,
                                                   vq2b, qsb2, qs2);
    nodes_kernel<<<dim3(64, 4), 256, 0, stream>>>(kxTg, qs2, ks2, npart);
    interp_kernel<<<dim3(64, 4), 256, 0, stream>>>(npart, qs2, attb);
    gemm2ln_kernel<<<256, 512, 0, stream>>>(attb, WpT, bp, x, ln_g, ln_b, out);
}

// Round 10
// 126.537 us; speedup vs baseline: 1.0169x; 1.0148x over previous
//
#include <hip/hip_runtime.h>
#include <cstddef>

#define TT 1024
#define DDIM 512
#define HH 8
#define NND 64           // interpolation nodes per (b,h): h^4 cubic error ~6e-5, safe
#define NS 68            // node row stride (floats): 64 d + Z at [64]

typedef __attribute__((ext_vector_type(8))) short bfrag;   // 8 bf16 (4 VGPRs)
typedef __attribute__((ext_vector_type(4))) float facc;    // 4 fp32 acc

#define SC2   2.8853900817779268f   // 2*log2(e)
#define L2E   1.4426950408889634f

static __device__ __forceinline__ unsigned bfrne(float f) {
    unsigned u = __float_as_uint(f);
    return (u + 0x7fffu + ((u >> 16) & 1u)) >> 16;
}
static __device__ __forceinline__ unsigned pack2rne(float a, float b) {
    return bfrne(a) | (bfrne(b) << 16);
}
static __device__ __forceinline__ unsigned pack2hu(float a, float b) {
    return ((__float_as_uint(a) + 0x8000u) >> 16) |
           ((__float_as_uint(b) + 0x8000u) & 0xffff0000u);
}
static __device__ __forceinline__ void gl2lds16(const void* g, void* l) {
    __builtin_amdgcn_global_load_lds(
        (const __attribute__((address_space(1))) unsigned int*)g,
        (__attribute__((address_space(3))) unsigned int*)l, 16, 0, 0);
}
// w from pre-multiplied t = exp2(z2_node)*exp2(kv2):  w = exp(tanh(z)) = e^{1-2/(t+1)}
static __device__ __forceinline__ float wt(float t) {
    float r = __builtin_amdgcn_rcpf(t + 1.f);
    return __builtin_amdgcn_exp2f(fmaf(r, -2.f * L2E, L2E));
}

// ---- K1: fused prepare ---------------------------------------------------------
__global__ __launch_bounds__(256) void prepare_kernel(
    const float* __restrict__ x, const float* __restrict__ Wk,
    const float* __restrict__ Wp, const float* __restrict__ Wq,
    const float* __restrict__ bq, const float* __restrict__ wm,
    unsigned short* __restrict__ xb, unsigned short* __restrict__ WkT,
    unsigned short* __restrict__ WpT, unsigned short* __restrict__ vq2b,
    float* __restrict__ qsb2)
{
    const int bx = blockIdx.x, tid = threadIdx.x;
    const int lane = tid & 63, wave = tid >> 6;
    if (bx < 2048) {
        const int row = bx * 4 + wave;
        const float4* xr = (const float4*)(x + (size_t)row * DDIM);
        float4 x0 = xr[lane * 2], x1 = xr[lane * 2 + 1];
        uint4 st;
        st.x = pack2rne(x0.x, x0.y); st.y = pack2rne(x0.z, x0.w);
        st.z = pack2rne(x1.x, x1.y); st.w = pack2rne(x1.z, x1.w);
        int p = lane ^ (row & 7);
        *(uint4*)(xb + (size_t)row * DDIM + p * 8) = st;
    } else if (bx < 2176) {
        int idx = bx - 2048;
        const float* src = (idx & 64) ? Wp : Wk;
        unsigned short* dst = (idx & 64) ? WpT : WkT;
        idx &= 63;
        const int n0 = (idx & 7) * 64, k0 = (idx >> 3) * 64;
        __shared__ float sT[64][65];
        #pragma unroll
        for (int it = 0; it < 4; ++it) {
            int task = it * 256 + tid;
            int kr = task >> 4, c4 = (task & 15) * 4;
            float4 v = *(const float4*)(src + (size_t)(k0 + kr) * DDIM + n0 + c4);
            sT[kr][c4] = v.x; sT[kr][c4 + 1] = v.y; sT[kr][c4 + 2] = v.z; sT[kr][c4 + 3] = v.w;
        }
        __syncthreads();
        #pragma unroll
        for (int it = 0; it < 2; ++it) {
            int task = it * 256 + tid;
            int n = task >> 3, kg = task & 7;
            unsigned u[4];
            #pragma unroll
            for (int jj = 0; jj < 4; ++jj)
                u[jj] = pack2rne(sT[kg * 8 + jj * 2][n], sT[kg * 8 + jj * 2 + 1][n]);
            int p = ((k0 >> 3) + kg) ^ (n & 7);
            uint4 st; st.x = u[0]; st.y = u[1]; st.z = u[2]; st.w = u[3];
            *(uint4*)(dst + (size_t)(n0 + n) * DDIM + p * 8) = st;
        }
    } else {
        int idx = (bx - 2176) * 4 + wave;   // 0..4095
        int h = idx >> 9, d = idx & 511;
        float v = Wq[(size_t)d * DDIM + h * 64 + lane] * wm[64 + lane];
        #pragma unroll
        for (int off = 32; off > 0; off >>= 1) v += __shfl_xor(v, off);
        if (lane == 0) vq2b[h * DDIM + d] = (unsigned short)bfrne(v * SC2);
        if (bx == 2176 && tid < HH) {
            float sb = 0.f;
            for (int j = 0; j < 64; ++j)
                sb = fmaf(bq[tid * 64 + j], wm[64 + j], sb);
            qsb2[tid] = sb * SC2;
        }
    }
}

// ---- K2: GEMM1 kx = xb @ WkT + bk. Tile 64 t x 128 n, grid 512 = 2 blocks/CU. --
__global__ __launch_bounds__(256) void gemm1_kernel(
    const unsigned short* __restrict__ A, const unsigned short* __restrict__ B,
    const float* __restrict__ bias, unsigned short* __restrict__ kxTg,
    float* __restrict__ ks2, const float* __restrict__ wm,
    const unsigned short* __restrict__ vq2b, const float* __restrict__ qsb2,
    float* __restrict__ qs2)
{
    // 2 bufs x (A 4096 | B 8192) = 24576 shorts + svq 1024; epi eT 2x4608 reuses buf0
    __shared__ __align__(16) unsigned short smem[25600];
    unsigned short* svq = smem + 24576;
    const int tid = threadIdx.x, lane = tid & 63, wave = tid >> 6;
    const int l15 = lane & 15, quad = lane >> 4;
    const int wr = wave >> 1, wc = wave & 1;           // 2x2 wave grid: 32 rows x 64 cols
    const int row0 = blockIdx.x * 64, colpair = blockIdx.y;
    const int h = colpair * 2 + wc, n0 = colpair * 128;

    const float qsbh = qsb2[h];
    float bvv[4], wmv[4];
    #pragma unroll
    for (int nt = 0; nt < 4; ++nt) {
        bvv[nt] = bias[h * 64 + nt * 16 + l15];
        wmv[nt] = wm[nt * 16 + l15] * SC2;
    }

    facc acc[2][4]; facc accq[2];
    #pragma unroll
    for (int i = 0; i < 2; ++i) {
        #pragma unroll
        for (int j = 0; j < 4; ++j) { acc[i][j][0]=0.f; acc[i][j][1]=0.f; acc[i][j][2]=0.f; acc[i][j][3]=0.f; }
        accq[i][0]=0.f; accq[i][1]=0.f; accq[i][2]=0.f; accq[i][3]=0.f;
    }

    if (tid < 128)
        gl2lds16(vq2b + colpair * 1024 + tid * 8, &svq[tid * 8]);

    auto stage = [&](int sel, int k0) {
        unsigned short* dA = smem + sel * 12288;
        unsigned short* dB = dA + 4096;
        #pragma unroll
        for (int it = 0; it < 2; ++it) {
            int g = it * 256 + tid;
            int r = g >> 3, kg = g & 7;
            gl2lds16(A + (size_t)(row0 + r) * 512 + k0 + kg * 8, &dA[g * 8]);
        }
        #pragma unroll
        for (int it = 0; it < 4; ++it) {
            int g = it * 256 + tid;
            int r = g >> 3, kg = g & 7;
            gl2lds16(B + (size_t)(n0 + r) * 512 + k0 + kg * 8, &dB[g * 8]);
        }
    };

    stage(0, 0);
    #pragma unroll
    for (int kt = 0; kt < 8; ++kt) {
        const int sel = kt & 1;
        if (kt < 7) {
            stage(sel ^ 1, (kt + 1) * 64);
            asm volatile("s_waitcnt vmcnt(6)" ::: "memory");
        } else {
            asm volatile("s_waitcnt vmcnt(0)" ::: "memory");
        }
        __builtin_amdgcn_s_barrier();
        __builtin_amdgcn_sched_barrier(0);
        const unsigned short* sA = smem + sel * 12288;
        const unsigned short* sB = sA + 4096;
        #pragma unroll
        for (int ks_ = 0; ks_ < 2; ++ks_) {
            int slot = (ks_ * 4 + quad) ^ (l15 & 7);
            bfrag a[2], b[4];
            #pragma unroll
            for (int i = 0; i < 2; ++i)
                a[i] = *(const bfrag*)&sA[(wr * 32 + i * 16 + l15) * 64 + slot * 8];
            #pragma unroll
            for (int nt = 0; nt < 4; ++nt)
                b[nt] = *(const bfrag*)&sB[(wc * 64 + nt * 16 + l15) * 64 + slot * 8];
            bfrag bvq = *(const bfrag*)&svq[wc * 512 + kt * 64 + ks_ * 32 + quad * 8];
            #pragma unroll
            for (int i = 0; i < 2; ++i) {
                #pragma unroll
                for (int nt = 0; nt < 4; ++nt)
                    acc[i][nt] = __builtin_amdgcn_mfma_f32_16x16x32_bf16(a[i], b[nt], acc[i][nt], 0, 0, 0);
                accq[i] = __builtin_amdgcn_mfma_f32_16x16x32_bf16(a[i], bvq, accq[i], 0, 0, 0);
            }
        }
        __builtin_amdgcn_s_barrier();
        __builtin_amdgcn_sched_barrier(0);
    }
    asm volatile("" ::: "memory");

    // ---- epilogue: bias, qs2/ks2, per-head LDS transpose, coalesced stores ----
    const int bb = row0 >> 10, t0 = row0 & 1023;
    float part[2][4];
    #pragma unroll
    for (int i = 0; i < 2; ++i)
        #pragma unroll
        for (int r = 0; r < 4; ++r) part[i][r] = 0.f;

    unsigned short* eT = smem + wc * 4608;   // per head [64 d][72 t-stride]
    #pragma unroll
    for (int i = 0; i < 2; ++i) {
        int tr = wr * 32 + i * 16 + quad * 4;
        #pragma unroll
        for (int nt = 0; nt < 4; ++nt) {
            int d = nt * 16 + l15;
            float v0 = acc[i][nt][0] + bvv[nt], v1 = acc[i][nt][1] + bvv[nt];
            float v2 = acc[i][nt][2] + bvv[nt], v3 = acc[i][nt][3] + bvv[nt];
            part[i][0] = fmaf(wmv[nt], v0, part[i][0]);
            part[i][1] = fmaf(wmv[nt], v1, part[i][1]);
            part[i][2] = fmaf(wmv[nt], v2, part[i][2]);
            part[i][3] = fmaf(wmv[nt], v3, part[i][3]);
            *(unsigned*)&eT[d * 72 + tr]     = pack2rne(v0, v1);
            *(unsigned*)&eT[d * 72 + tr + 2] = pack2rne(v2, v3);
        }
    }
    #pragma unroll
    for (int i = 0; i < 2; ++i)
        #pragma unroll
        for (int r = 0; r < 4; ++r) {
            float p = part[i][r];
            p += __shfl_xor(p, 1); p += __shfl_xor(p, 2);
            p += __shfl_xor(p, 4); p += __shfl_xor(p, 8);
            if (l15 == 0) {
                size_t o = (size_t)(bb * HH + h) * TT + t0 + wr * 32 + i * 16 + quad * 4 + r;
                ks2[o] = p;
                qs2[o] = accq[i][r] + qsbh;
            }
        }
    __syncthreads();
    #pragma unroll
    for (int it = 0; it < 4; ++it) {
        int task = it * 256 + tid;
        int hh = task >> 9, rem = task & 511;
        int col = rem >> 3, seg = rem & 7;
        uint4 v = *(const uint4*)&smem[hh * 4608 + col * 72 + seg * 8];
        int hg = colpair * 2 + hh;
        int g = (t0 >> 3) + seg;
        int p = g ^ (col & 7);
        *(uint4*)(kxTg + ((size_t)(bb * HH + hg) * 64 + col) * TT + p * 8) = v;
    }
}

// ---- K3a: node-curve partials. grid (64 bh, 4 kq) = 256 blocks. NND=64. -------
__global__ __launch_bounds__(256) void nodes_kernel(
    const unsigned short* __restrict__ kxTg, const float* __restrict__ qs2,
    const float* __restrict__ ks2, float* __restrict__ npart)
{
    __shared__ __align__(16) unsigned short kxT[16384]; // 32 KB
    __shared__ float tks[256];
    __shared__ float redl[8];
    const int bh = blockIdx.x, kq = blockIdx.y;
    const int tid = threadIdx.x, lane = tid & 63, wave = tid >> 6;
    const int l15 = lane & 15, quad = lane >> 4;
    const unsigned short* kxbase = kxTg + (size_t)bh * 64 * TT;

    #pragma unroll
    for (int it = 0; it < 8; ++it) {
        int g = it * 256 + tid;
        int d = g >> 5, j = g & 31;
        gl2lds16(kxbase + (size_t)d * TT + kq * 256 + j * 8, &kxT[g * 8]);
    }
    float ksv = ks2[(size_t)bh * TT + kq * 256 + tid];
    float4 q4 = ((const float4*)(qs2 + (size_t)bh * TT))[tid];
    tks[tid] = __builtin_amdgcn_exp2f(ksv);
    float mn = fminf(fminf(q4.x, q4.y), fminf(q4.z, q4.w));
    float mx = fmaxf(fmaxf(q4.x, q4.y), fmaxf(q4.z, q4.w));
    #pragma unroll
    for (int off = 32; off > 0; off >>= 1) {
        mn = fminf(mn, __shfl_xor(mn, off));
        mx = fmaxf(mx, __shfl_xor(mx, off));
    }
    if (lane == 0) { redl[wave] = mn; redl[4 + wave] = mx; }
    __syncthreads();   // drains stage vmcnt + LDS writes
    const float mnv = fminf(fminf(redl[0], redl[1]), fminf(redl[2], redl[3]));
    const float mxv = fmaxf(fmaxf(redl[4], redl[5]), fmaxf(redl[6], redl[7]));
    const float h2v = (mxv - mnv) * (1.f / 63.f);
    const float z0 = mnv + (wave * 16 + l15) * h2v;    // node = wave*16 + l15
    const float tz = __builtin_amdgcn_exp2f(z0);

    facc acc[4]; facc accZ;
    #pragma unroll
    for (int i = 0; i < 4; ++i) { acc[i][0]=0.f; acc[i][1]=0.f; acc[i][2]=0.f; acc[i][3]=0.f; }
    accZ[0]=0.f; accZ[1]=0.f; accZ[2]=0.f; accZ[3]=0.f;
    bfrag ones;
    #pragma unroll
    for (int j = 0; j < 8; ++j) ones[j] = (short)0x3F80;

    #pragma unroll
    for (int kst = 0; kst < 8; ++kst) {
        const float* kvp = &tks[kst * 32 + quad * 8];
        float4 kv0 = *(const float4*)kvp;
        float4 kv1 = *(const float4*)(kvp + 4);
        int slot = (kst * 4 + quad) ^ (l15 & 7);
        bfrag bf_[4];
        #pragma unroll
        for (int dt = 0; dt < 4; ++dt)
            bf_[dt] = *(const bfrag*)&kxT[(dt * 16 + l15) * 256 + slot * 8];
        union { unsigned u[4]; bfrag f; } afu;
        afu.u[0] = pack2hu(wt(tz * kv0.x), wt(tz * kv0.y));
        afu.u[1] = pack2hu(wt(tz * kv0.z), wt(tz * kv0.w));
        afu.u[2] = pack2hu(wt(tz * kv1.x), wt(tz * kv1.y));
        afu.u[3] = pack2hu(wt(tz * kv1.z), wt(tz * kv1.w));
        #pragma unroll
        for (int dt = 0; dt < 4; ++dt)
            acc[dt] = __builtin_amdgcn_mfma_f32_16x16x32_bf16(afu.f, bf_[dt], acc[dt], 0, 0, 0);
        accZ = __builtin_amdgcn_mfma_f32_16x16x32_bf16(afu.f, ones, accZ, 0, 0, 0);
    }
    float* dst = npart + (size_t)(bh * 4 + kq) * (NND * NS);
    #pragma unroll
    for (int r = 0; r < 4; ++r) {
        int node = wave * 16 + quad * 4 + r;
        #pragma unroll
        for (int dt = 0; dt < 4; ++dt)
            dst[node * NS + dt * 16 + l15] = acc[dt][r];
        if (l15 == 0) dst[node * NS + 64] = accZ[r];
    }
}

// ---- K3b: sum partials + fused cubic interp. grid (64 bh, 4 tq). NND=64. ------
__global__ __launch_bounds__(256) void interp_kernel(
    const float* __restrict__ npart, const float* __restrict__ qs2,
    unsigned short* __restrict__ attb)
{
    __shared__ __align__(16) float nodes[NND * NS];   // 17.4 KB
    __shared__ float redl[8];
    const int bh = blockIdx.x, tq = blockIdx.y;
    const int b = bh >> 3, h = bh & 7;
    const int tid = threadIdx.x, lane = tid & 63, wave = tid >> 6;

    // minmax over qs2 row — ops IDENTICAL to nodes_kernel -> bitwise-same mnv/mxv
    float4 q4 = ((const float4*)(qs2 + (size_t)bh * TT))[tid];
    float mn = fminf(fminf(q4.x, q4.y), fminf(q4.z, q4.w));
    float mx = fmaxf(fmaxf(q4.x, q4.y), fmaxf(q4.z, q4.w));
    #pragma unroll
    for (int off = 32; off > 0; off >>= 1) {
        mn = fminf(mn, __shfl_xor(mn, off));
        mx = fmaxf(mx, __shfl_xor(mx, off));
    }
    if (lane == 0) { redl[wave] = mn; redl[4 + wave] = mx; }
    __syncthreads();
    const float mnv = fminf(fminf(redl[0], redl[1]), fminf(redl[2], redl[3]));
    const float mxv = fmaxf(fmaxf(redl[4], redl[5]), fmaxf(redl[6], redl[7]));
    const float invv = 63.f / fmaxf(mxv - mnv, 1e-12f);

    // sum 4 k-quarter partials (fixed order -> deterministic)
    const float4* p0 = (const float4*)(npart + (size_t)(bh * 4 + 0) * (NND * NS));
    const float4* p1 = (const float4*)(npart + (size_t)(bh * 4 + 1) * (NND * NS));
    const float4* p2 = (const float4*)(npart + (size_t)(bh * 4 + 2) * (NND * NS));
    const float4* p3 = (const float4*)(npart + (size_t)(bh * 4 + 3) * (NND * NS));
    #pragma unroll
    for (int it = 0; it < 5; ++it) {
        int g = it * 256 + tid;
        if (g < (NND * NS) / 4) {
            float4 a = p0[g], bb4 = p1[g], c = p2[g], d = p3[g];
            float4 s;
            s.x = a.x + bb4.x + c.x + d.x;
            s.y = a.y + bb4.y + c.y + d.y;
            s.z = a.z + bb4.z + c.z + d.z;
            s.w = a.w + bb4.w + c.w + d.w;
            ((float4*)nodes)[g] = s;
        }
    }
    __syncthreads();

    const float* qsp = qs2 + (size_t)bh * TT;
    #pragma unroll 2
    for (int it = 0; it < 16; ++it) {
        int task = it * 256 + tid;
        int t = tq * 256 + (task >> 4), dp = task & 15;
        float qv = qsp[t];
        float u = (qv - mnv) * invv;
        int i = (int)floorf(u) - 1;
        i = i < 0 ? 0 : (i > NND - 4 ? NND - 4 : i);
        float s = u - (float)i;
        float s1 = s - 1.f, s2 = s - 2.f, s3 = s - 3.f;
        float w0 = -s1 * s2 * s3 * (1.f / 6.f);
        float w1 = s * s2 * s3 * 0.5f;
        float w2 = -s * s1 * s3 * 0.5f;
        float w3 = s * s1 * s2 * (1.f / 6.f);
        const float* base = &nodes[i * NS];
        float4 v0 = *(const float4*)(base + 4 * dp);
        float4 v1 = *(const float4*)(base + NS + 4 * dp);
        float4 v2 = *(const float4*)(base + 2 * NS + 4 * dp);
        float4 v3 = *(const float4*)(base + 3 * NS + 4 * dp);
        float zz = w0 * base[64] + w1 * base[NS + 64] + w2 * base[2 * NS + 64] + w3 * base[3 * NS + 64];
        float ox = w0 * v0.x + w1 * v1.x + w2 * v2.x + w3 * v3.x;
        float oy = w0 * v0.y + w1 * v1.y + w2 * v2.y + w3 * v3.y;
        float oz = w0 * v0.z + w1 * v1.z + w2 * v2.z + w3 * v3.z;
        float ow = w0 * v0.w + w1 * v1.w + w2 * v2.w + w3 * v3.w;
        float rz = __builtin_amdgcn_rcpf(zz);
        uint2 st;
        st.x = pack2rne(ox * rz, oy * rz);
        st.y = pack2rne(oz * rz, ow * rz);
        int row = b * TT + t;
        int col = h * 64 + 4 * dp;
        int p = (col >> 3) ^ (row & 7);
        *(uint2*)&attb[(size_t)row * DDIM + p * 8 + (col & 7)] = st;
    }
}

// ---- K4: GEMM2 proj = attb @ WpT + bp. Tile 64x128, grid 512 = 2 blocks/CU. ---
__global__ __launch_bounds__(256) void gemm2_kernel(
    const unsigned short* __restrict__ A, const unsigned short* __restrict__ B,
    const float* __restrict__ bias, unsigned short* __restrict__ yb)
{
    __shared__ __align__(16) unsigned short smem[24576]; // 2x(A|B); epi: yT 64x136
    const int tid = threadIdx.x, lane = tid & 63, wave = tid >> 6;
    const int l15 = lane & 15, quad = lane >> 4;
    const int wr = wave >> 1, wc = wave & 1;
    const int row0 = blockIdx.x * 64, col0 = blockIdx.y * 128;

    float bvv[4];
    #pragma unroll
    for (int nt = 0; nt < 4; ++nt) bvv[nt] = bias[col0 + wc * 64 + nt * 16 + l15];

    facc acc[2][4];
    #pragma unroll
    for (int i = 0; i < 2; ++i)
        #pragma unroll
        for (int j = 0; j < 4; ++j) { acc[i][j][0]=0.f; acc[i][j][1]=0.f; acc[i][j][2]=0.f; acc[i][j][3]=0.f; }

    auto stage = [&](int sel, int k0) {
        unsigned short* dA = smem + sel * 12288;
        unsigned short* dB = dA + 4096;
        #pragma unroll
        for (int it = 0; it < 2; ++it) {
            int g = it * 256 + tid;
            int r = g >> 3, kg = g & 7;
            gl2lds16(A + (size_t)(row0 + r) * 512 + k0 + kg * 8, &dA[g * 8]);
        }
        #pragma unroll
        for (int it = 0; it < 4; ++it) {
            int g = it * 256 + tid;
            int r = g >> 3, kg = g & 7;
            gl2lds16(B + (size_t)(col0 + r) * 512 + k0 + kg * 8, &dB[g * 8]);
        }
    };

    stage(0, 0);
    #pragma unroll
    for (int kt = 0; kt < 8; ++kt) {
        const int sel = kt & 1;
        if (kt < 7) {
            stage(sel ^ 1, (kt + 1) * 64);
            asm volatile("s_waitcnt vmcnt(6)" ::: "memory");
        } else {
            asm volatile("s_waitcnt vmcnt(0)" ::: "memory");
        }
        __builtin_amdgcn_s_barrier();
        __builtin_amdgcn_sched_barrier(0);
        const unsigned short* sA = smem + sel * 12288;
        const unsigned short* sB = sA + 4096;
        #pragma unroll
        for (int ks_ = 0; ks_ < 2; ++ks_) {
            int slot = (ks_ * 4 + quad) ^ (l15 & 7);
            bfrag a[2], b[4];
            #pragma unroll
            for (int i = 0; i < 2; ++i)
                a[i] = *(const bfrag*)&sA[(wr * 32 + i * 16 + l15) * 64 + slot * 8];
            #pragma unroll
            for (int nt = 0; nt < 4; ++nt)
                b[nt] = *(const bfrag*)&sB[(wc * 64 + nt * 16 + l15) * 64 + slot * 8];
            #pragma unroll
            for (int i = 0; i < 2; ++i)
                #pragma unroll
                for (int nt = 0; nt < 4; ++nt)
                    acc[i][nt] = __builtin_amdgcn_mfma_f32_16x16x32_bf16(a[i], b[nt], acc[i][nt], 0, 0, 0);
        }
        __builtin_amdgcn_s_barrier();
        __builtin_amdgcn_sched_barrier(0);
    }
    asm volatile("" ::: "memory");

    unsigned short* yT = smem;   // [row][col] stride 136
    #pragma unroll
    for (int i = 0; i < 2; ++i) {
        #pragma unroll
        for (int nt = 0; nt < 4; ++nt) {
            int col = wc * 64 + nt * 16 + l15;
            #pragma unroll
            for (int r = 0; r < 4; ++r) {
                int row = wr * 32 + i * 16 + quad * 4 + r;
                yT[row * 136 + col] = (unsigned short)bfrne(acc[i][nt][r] + bvv[nt]);
            }
        }
    }
    __syncthreads();
    #pragma unroll
    for (int it = 0; it < 4; ++it) {
        int task = it * 256 + tid;
        int row = task >> 4, seg = task & 15;
        uint4 v = *(const uint4*)&yT[row * 136 + seg * 8];
        *(uint4*)(yb + (size_t)(row0 + row) * DDIM + col0 + seg * 8) = v;
    }
}

// ---- K5: residual (bf16 xb) + LayerNorm ---------------------------------------
__global__ __launch_bounds__(256) void ln_kernel(
    const unsigned short* __restrict__ yb, const unsigned short* __restrict__ xb,
    const float* __restrict__ g, const float* __restrict__ bet,
    float* __restrict__ out)
{
    const int tid = threadIdx.x, lane = tid & 63, wave = tid >> 6;
    const int row = blockIdx.x * 4 + wave;
    uint4 pv = *(const uint4*)(yb + (size_t)row * DDIM + lane * 8);
    int pgr = lane ^ (row & 7);                    // unswizzle xb granule
    uint4 xv = *(const uint4*)(xb + (size_t)row * DDIM + pgr * 8);
    float y[8];
    const unsigned* pu = (const unsigned*)&pv;
    const unsigned* xu = (const unsigned*)&xv;
    #pragma unroll
    for (int j = 0; j < 4; ++j) {
        y[2*j]   = __uint_as_float(pu[j] << 16)        + __uint_as_float(xu[j] << 16);
        y[2*j+1] = __uint_as_float(pu[j] & 0xffff0000u) + __uint_as_float(xu[j] & 0xffff0000u);
    }
    float s = 0.f, s2 = 0.f;
    #pragma unroll
    for (int i = 0; i < 8; ++i) { s += y[i]; s2 = fmaf(y[i], y[i], s2); }
    #pragma unroll
    for (int off = 32; off > 0; off >>= 1) {
        s += __shfl_xor(s, off);
        s2 += __shfl_xor(s2, off);
    }
    float mu = s * (1.f / 512.f);
    float var = s2 * (1.f / 512.f) - mu * mu;
    float inv = rsqrtf(var + 1e-5f);
    const float4* gp = (const float4*)(g + lane * 8);
    const float4* bp = (const float4*)(bet + lane * 8);
    float4 g0 = gp[0], g1 = gp[1], b0 = bp[0], b1 = bp[1];
    float4 o0, o1;
    o0.x = (y[0] - mu) * inv * g0.x + b0.x; o0.y = (y[1] - mu) * inv * g0.y + b0.y;
    o0.z = (y[2] - mu) * inv * g0.z + b0.z; o0.w = (y[3] - mu) * inv * g0.w + b0.w;
    o1.x = (y[4] - mu) * inv * g1.x + b1.x; o1.y = (y[5] - mu) * inv * g1.y + b1.y;
    o1.z = (y[6] - mu) * inv * g1.z + b1.z; o1.w = (y[7] - mu) * inv * g1.w + b1.w;
    float4* op = (float4*)(out + (size_t)row * DDIM);
    op[lane * 2] = o0; op[lane * 2 + 1] = o1;
}

// ---- launch -------------------------------------------------------------------
extern "C" void kernel_launch(void* const* d_in, const int* in_sizes, int n_in,
                              void* d_out, int out_size, void* d_ws, size_t ws_size,
                              hipStream_t stream)
{
    const float* x    = (const float*)d_in[0];
    const float* Wq   = (const float*)d_in[1];
    const float* bq   = (const float*)d_in[2];
    const float* Wk   = (const float*)d_in[3];
    const float* bk   = (const float*)d_in[4];
    const float* Wp   = (const float*)d_in[5];
    const float* bp   = (const float*)d_in[6];
    const float* wm   = (const float*)d_in[7];
    const float* ln_g = (const float*)d_in[8];
    const float* ln_b = (const float*)d_in[9];
    float* out = (float*)d_out;

    float* ws = (float*)d_ws;
    float*          qsb2 = ws;                                    // 64
    unsigned short* vq2b = (unsigned short*)(ws + 64);            // 2048 f
    unsigned short* WkT  = (unsigned short*)(ws + 2112);          // 131072 f
    unsigned short* WpT  = (unsigned short*)(ws + 133184);        // 131072 f
    unsigned short* xb   = (unsigned short*)(ws + 264256);        // 2097152 f
    unsigned short* kxTg = (unsigned short*)(ws + 2361408);       // 2097152 f
    float*          qs2  = ws + 4458560;                          // 65536
    float*          ks2  = ws + 4524096;                          // 65536
    unsigned short* attb = (unsigned short*)(ws + 4589632);       // 2097152 f
    unsigned short* yb   = (unsigned short*)(ws + 6686784);       // 2097152 f
    float*          npart = ws + 8783936;                         // 64*4*64*68 = 1114112 f

    prepare_kernel<<<3200, 256, 0, stream>>>(x, Wk, Wp, Wq, bq, wm,
                                             xb, WkT, WpT, vq2b, qsb2);
    gemm1_kernel<<<dim3(128, 4), 256, 0, stream>>>(xb, WkT, bk, kxTg, ks2, wm,
                                                   vq2b, qsb2, qs2);
    nodes_kernel<<<dim3(64, 4), 256, 0, stream>>>(kxTg, qs2, ks2, npart);
    interp_kernel<<<dim3(64, 4), 256, 0, stream>>>(npart, qs2, attb);
    gemm2_kernel<<<dim3(128, 4), 256, 0, stream>>>(attb, WpT, bp, yb);
    ln_kernel<<<2048, 256, 0, stream>>>(yb, xb, ln_g, ln_b, out);
}